// Round 1
// 550.547 us; speedup vs baseline: 1.2919x; 1.2919x over previous
//
#include <hip/hip_runtime.h>
#include <hip/hip_bf16.h>

#define HW 784
#define WD 28
#define NPX (56 * HW)          // 43904 deform/offconv pixels
#define PXBLK 172              // ceil(43904/256)
#define PLANE (56 * 64 * HW)   // 2,809,856 floats: one full plane
#define PADPX 1024             // 32x32 padded spatial (halo 2)

using short8 = __attribute__((ext_vector_type(8))) short;
using f32x4  = __attribute__((ext_vector_type(4))) float;

// ---------------------------------------------------------------------------
// Prep: fold BN into transposed weight layouts + MFMA-fragment-order bf16
// weights for the offset convs and the fused deform GEMM.
// wBs[tap][chunk][ntile][lane][j] (bf16): B[k=chunk*32+(lane>>4)*8+j][oc=ntile*16+(lane&15)]
// wBd: same frag layout, 34 taps (9 from def3_w, 25 from def5_w), NT=4.
// ---------------------------------------------------------------------------
__global__ void k_prep(
    const float* __restrict__ w_down, const float* __restrict__ b_down,
    const float* __restrict__ bn1_g, const float* __restrict__ bn1_b,
    const float* __restrict__ bn1_m, const float* __restrict__ bn1_v,
    const float* __restrict__ tconv_w, const float* __restrict__ tconv_b,
    const float* __restrict__ bnt_g, const float* __restrict__ bnt_b,
    const float* __restrict__ bnt_m, const float* __restrict__ bnt_v,
    const float* __restrict__ off3_w, const float* __restrict__ def3_w,
    const float* __restrict__ off5_w, const float* __restrict__ def5_w,
    const float* __restrict__ conv1_w, const float* __restrict__ conv1_b,
    const float* __restrict__ bn3_g, const float* __restrict__ bn3_b,
    const float* __restrict__ bn3_m, const float* __restrict__ bn3_v,
    const float* __restrict__ conv_w, const float* __restrict__ conv_b,
    const float* __restrict__ bn2_g, const float* __restrict__ bn2_b,
    const float* __restrict__ bn2_m, const float* __restrict__ bn2_v,
    float* __restrict__ wdownT, float* __restrict__ bias1,
    float* __restrict__ wtT, float* __restrict__ AtBt,
    __hip_bfloat16* __restrict__ wBs3, __hip_bfloat16* __restrict__ wBs5,
    __hip_bfloat16* __restrict__ wBd,
    float* __restrict__ c1T, float* __restrict__ B3,
    float* __restrict__ gwT, float* __restrict__ Bg)
{
  const int tid = blockIdx.x * blockDim.x + threadIdx.x;
  const int nth = gridDim.x * blockDim.x;
  for (int i = tid; i < 256 * 64; i += nth) {
    int c = i >> 6, cr = i & 63;
    float s = bn1_g[cr] / sqrtf(bn1_v[cr] + 1e-5f);
    wdownT[i] = w_down[cr * 256 + c] * s;
  }
  for (int i = tid; i < 64; i += nth) {
    float s = bn1_g[i] / sqrtf(bn1_v[i] + 1e-5f);
    bias1[i] = (b_down[i] - bn1_m[i]) * s + bn1_b[i];
  }
  for (int i = tid; i < 192 * 9 * 64; i += nth) {
    int cc = i / (9 * 64); int tap = (i / 64) % 9; int o = i & 63;
    int dt = cc >> 6, c = cc & 63;
    wtT[i] = tconv_w[o * 1728 + c * 27 + dt * 9 + tap];
  }
  for (int i = tid; i < 64; i += nth) {
    float s = bnt_g[i] / sqrtf(bnt_v[i] + 1e-5f);
    AtBt[i] = s * 0.125f;
    AtBt[64 + i] = (tconv_b[i] - bnt_m[i]) * s + bnt_b[i];
  }
  // off3 MFMA B-frags: K2=9, NT=2 (ocpad 32). total 9*2*2*512 = 18432
  for (int i = tid; i < 9 * 2 * 2 * 512; i += nth) {
    int j = i & 7; int lane = (i >> 3) & 63;
    int rest = i >> 9; int nt = rest % 2; rest /= 2;
    int chunk = rest & 1; int tap = rest >> 1;
    int c = chunk * 32 + ((lane >> 4) << 3) + j;
    int oc = nt * 16 + (lane & 15);
    float v = (oc < 18) ? off3_w[oc * 576 + c * 9 + tap] : 0.f;
    wBs3[i] = __float2bfloat16(v);
  }
  // off5 MFMA B-frags: K2=25, NT=4 (ocpad 64). total 25*2*4*512 = 102400
  for (int i = tid; i < 25 * 2 * 4 * 512; i += nth) {
    int j = i & 7; int lane = (i >> 3) & 63;
    int rest = i >> 9; int nt = rest % 4; rest /= 4;
    int chunk = rest & 1; int tap = rest >> 1;
    int c = chunk * 32 + ((lane >> 4) << 3) + j;
    int oc = nt * 16 + (lane & 15);
    float v = (oc < 50) ? off5_w[oc * 1600 + c * 25 + tap] : 0.f;
    wBs5[i] = __float2bfloat16(v);
  }
  // fused deform B-frags: 34 taps (0..8 = def3, 9..33 = def5), NT=4 (oc=64)
  for (int i = tid; i < 34 * 2 * 4 * 512; i += nth) {
    int j = i & 7; int lane = (i >> 3) & 63;
    int rest = i >> 9; int nt = rest & 3; rest >>= 2;
    int chunk = rest & 1; int tap = rest >> 1;
    int c = chunk * 32 + ((lane >> 4) << 3) + j;
    int oc = nt * 16 + (lane & 15);
    float v = (tap < 9) ? def3_w[oc * 576 + c * 9 + tap]
                        : def5_w[oc * 1600 + c * 25 + (tap - 9)];
    wBd[i] = __float2bfloat16(v);
  }
  for (int i = tid; i < 64 * 64; i += nth) {
    int c = i >> 6, o = i & 63;
    float s = bn3_g[o] / sqrtf(bn3_v[o] + 1e-5f);
    c1T[i] = conv1_w[o * 64 + c] * s;
  }
  for (int i = tid; i < 64; i += nth) {
    float s = bn3_g[i] / sqrtf(bn3_v[i] + 1e-5f);
    B3[i] = (conv1_b[i] - bn3_m[i]) * s + bn3_b[i];
  }
  for (int i = tid; i < 64 * 256; i += nth) {
    int c = i >> 8, co = i & 255;
    float s = bn2_g[co] / sqrtf(bn2_v[co] + 1e-5f);
    gwT[i] = conv_w[co * 64 + c] * s;
  }
  for (int i = tid; i < 256; i += nth) {
    float s = bn2_g[i] / sqrtf(bn2_v[i] + 1e-5f);
    Bg[i] = (conv_b[i] - bn2_m[i]) * s + bn2_b[i];
  }
}

// ---------------------------------------------------------------------------
// Zero the padded bf16 image (halo must be 0 every call; ws is re-poisoned).
// 56*1024*64 bf16 = 458752 float4.
// ---------------------------------------------------------------------------
__global__ void k_zerob(float4* __restrict__ p)
{
  p[blockIdx.x * 256 + threadIdx.x] = make_float4(0.f, 0.f, 0.f, 0.f);
}

// ---------------------------------------------------------------------------
// 1x1 down conv (256->64) + BN fold. px-flat grid (196, o-split 2).
// ---------------------------------------------------------------------------
__global__ __launch_bounds__(256) void k_down(
    const float* __restrict__ x, const float* __restrict__ wdownT,
    const float* __restrict__ bias1, float* __restrict__ out)
{
  __shared__ float wl[256 * 32];            // 32 KB
  const int tid = threadIdx.x;
  const int o0 = blockIdx.y * 32;
  for (int i = tid; i < 2048; i += 256) {
    int c = i >> 3, q = i & 7;
    ((float4*)wl)[i] = *(const float4*)(wdownT + c * 64 + o0 + q * 4);
  }
  __syncthreads();
  const int gpx = blockIdx.x * 256 + tid;   // < 50176 exact
  const int f = gpx / HW, px = gpx % HW;
  const float* xp = x + (size_t)f * 256 * HW + px;
  float acc[32];
#pragma unroll
  for (int j = 0; j < 32; j++) acc[j] = 0.f;
#pragma unroll 4
  for (int c = 0; c < 256; c++) {
    float xv = xp[c * HW];
    const float* wr = &wl[c * 32];
#pragma unroll
    for (int j = 0; j < 32; j++) acc[j] += xv * wr[j];
  }
  float* op = out + (size_t)f * 64 * HW + px;
#pragma unroll
  for (int j = 0; j < 32; j++) op[(o0 + j) * HW] = acc[j] + bias1[o0 + j];
}

// ---------------------------------------------------------------------------
// Transpose post frames to px-major: xT[n][px][c] (f32, for deform) and
// padded bf16 xTbP[n][(py+2)*32+(px+2)][c] (for MFMA offconvs).
// ---------------------------------------------------------------------------
__global__ __launch_bounds__(256) void k_xpose(
    const float* __restrict__ out_b, float* __restrict__ xT,
    __hip_bfloat16* __restrict__ xTbP)
{
  __shared__ float t[64 * 65];
  const int tid = threadIdx.x;
  const int lane = tid & 63, grp = tid >> 6;
  const int n = blockIdx.x;
  const int f = (n / 7) * 8 + (n % 7) + 1;
  const int px0 = blockIdx.y * 64;
  const float* sb = out_b + (size_t)f * 64 * HW;
#pragma unroll
  for (int c = grp; c < 64; c += 4) {
    int px = px0 + lane;
    t[c * 65 + lane] = (px < HW) ? sb[c * HW + px] : 0.f;
  }
  __syncthreads();
#pragma unroll
  for (int r = grp; r < 64; r += 4) {
    int px = px0 + r;
    if (px < HW) {
      float v = t[lane * 65 + r];
      xT[((size_t)n * HW + px) * 64 + lane] = v;
      int py = px / WD, pxc = px % WD;
      xTbP[((size_t)n * PADPX + (py + 2) * 32 + (pxc + 2)) * 64 + lane] =
          __float2bfloat16(v);
    }
  }
}

// ---------------------------------------------------------------------------
// U planes for collapsed temporal conv.
// ---------------------------------------------------------------------------
__global__ void k_makeU(const float* __restrict__ out, float* __restrict__ U)
{
  const int idx = blockIdx.x * 256 + threadIdx.x;
  const int b = idx / (64 * HW);
  const int r = idx % (64 * HW);
  const float* p = out + (size_t)b * 8 * 64 * HW + r;
  float v0 = p[0];
  float s = v0, v = v0;
#pragma unroll
  for (int t = 1; t < 8; t++) { v = p[t * 64 * HW]; s += v; }
  float* u = U + (size_t)b * 192 * HW + r;
  u[0] = s - v;
  u[64 * HW] = s;
  u[128 * HW] = s - v0;
}

// ---------------------------------------------------------------------------
// Collapsed temporal conv: 3x3, 192->64. o-groups of 4 (16 z-blocks).
// ---------------------------------------------------------------------------
__global__ __launch_bounds__(256) void k_tconv(
    const float* __restrict__ U, const float* __restrict__ wtT,
    const float* __restrict__ AtBt, float* __restrict__ t_out)
{
  __shared__ float wl[16 * 9 * 4];
  const int tid = threadIdx.x;
  const int b = blockIdx.x;
  const int px = blockIdx.y * 256 + tid;
  const int o0 = blockIdx.z * 4;
  const bool act = px < HW;
  const int pxe = act ? px : 0;
  const int y = pxe / WD, x = pxe % WD;
  int lin[9]; float msk[9];
#pragma unroll
  for (int t = 0; t < 9; t++) {
    int iy = y + t / 3 - 1, ix = x + t % 3 - 1;
    bool ok = iy >= 0 && iy < WD && ix >= 0 && ix < WD;
    lin[t] = min(max(iy, 0), WD - 1) * WD + min(max(ix, 0), WD - 1);
    msk[t] = ok ? 1.f : 0.f;
  }
  float acc[4];
#pragma unroll
  for (int j = 0; j < 4; j++) acc[j] = 0.f;
  const float* ub = U + (size_t)b * 192 * HW;
  for (int ccb = 0; ccb < 12; ccb++) {
    __syncthreads();
    for (int i = tid; i < 576; i += 256) {
      int ccL = i / 36; int rr = i % 36; int tap = rr >> 2; int j = rr & 3;
      wl[i] = wtT[((ccb * 16 + ccL) * 9 + tap) * 64 + o0 + j];
    }
    __syncthreads();
    for (int ccL = 0; ccL < 16; ccL++) {
      const float* p = ub + (ccb * 16 + ccL) * HW;
      float v[9];
#pragma unroll
      for (int t = 0; t < 9; t++) v[t] = p[lin[t]] * msk[t];
      const float* wr = &wl[ccL * 36];
#pragma unroll
      for (int t = 0; t < 9; t++)
#pragma unroll
        for (int j = 0; j < 4; j++) acc[j] += v[t] * wr[t * 4 + j];
    }
  }
  if (act) {
#pragma unroll
    for (int j = 0; j < 4; j++) {
      int o = o0 + j;
      t_out[(size_t)(b * 64 + o) * HW + px] = acc[j] * AtBt[o] + AtBt[64 + o];
    }
  }
}

// ---------------------------------------------------------------------------
// Offset convs as implicit-GEMM bf16 MFMA (16x16x32).
// Block = 64 px (4 waves x 16 rows) x OCpad (NT*16). K = K2*64 over
// (tap, c-chunk). A from padded px-major bf16 image (borders = exact 0),
// B from pre-swizzled frag-order weights staged in LDS (1 ds_read_b128/frag).
// Epilogue via LDS transpose for coalesced f32 stores.
// ---------------------------------------------------------------------------
template <int KS, int PAD, int OC, int NT, int TAPBLK>
__global__ __launch_bounds__(256) void k_offconv_mfma(
    const __hip_bfloat16* __restrict__ xTbP,
    const __hip_bfloat16* __restrict__ wBs,
    const float* __restrict__ bias, float* __restrict__ dst)
{
  constexpr int K2 = KS * KS;
  __shared__ short bs[TAPBLK * NT * 1024];   // B frags, 2*NT KB per tap
  __shared__ float ct[NT * 16 * 65];         // C tile [ocpad][px(64)+pad]
  const int tid = threadIdx.x;
  const int w = tid >> 6, lane = tid & 63;
  const int quad = lane >> 4, mrow = lane & 15;
  const int gpx = blockIdx.x * 64 + w * 16 + mrow;   // A-row pixel
  const int n = gpx / HW, px = gpx % HW;
  const int y = px / WD, x = px % WD;
  const short* xb = (const short*)xTbP + ((size_t)n * PADPX) * 64;
  f32x4 acc[NT];
#pragma unroll
  for (int nt = 0; nt < NT; nt++) acc[nt] = (f32x4){0.f, 0.f, 0.f, 0.f};

  for (int tb = 0; tb < K2; tb += TAPBLK) {
    __syncthreads();
    for (int i = tid; i < TAPBLK * NT * 128; i += 256)
      ((float4*)bs)[i] = ((const float4*)(wBs + (size_t)tb * NT * 1024))[i];
    __syncthreads();
#pragma unroll
    for (int t2 = 0; t2 < TAPBLK; t2++) {
      int tap = tb + t2;
      if (K2 % TAPBLK != 0 && tap >= K2) break;
      int ty = tap / KS, tx = tap % KS;
      int sp = (y + ty + (2 - PAD)) * 32 + (x + tx + (2 - PAD));
      const short* ap = xb + sp * 64 + quad * 8;
      short8 a0 = *(const short8*)(ap);
      short8 a1 = *(const short8*)(ap + 32);
      const short* bp = bs + t2 * NT * 1024;
#pragma unroll
      for (int nt = 0; nt < NT; nt++) {
        short8 b0 = *(const short8*)(bp + nt * 512 + lane * 8);
        acc[nt] = __builtin_amdgcn_mfma_f32_16x16x32_bf16(a0, b0, acc[nt], 0, 0, 0);
      }
#pragma unroll
      for (int nt = 0; nt < NT; nt++) {
        short8 b1 = *(const short8*)(bp + (NT + nt) * 512 + lane * 8);
        acc[nt] = __builtin_amdgcn_mfma_f32_16x16x32_bf16(a1, b1, acc[nt], 0, 0, 0);
      }
    }
  }
  // C/D frag: col(oc) = lane&15, row(px) = quad*4 + reg
  __syncthreads();
#pragma unroll
  for (int nt = 0; nt < NT; nt++) {
    int oc_l = nt * 16 + mrow;
#pragma unroll
    for (int reg = 0; reg < 4; reg++) {
      int pxr = w * 16 + quad * 4 + reg;
      ct[oc_l * 65 + pxr] = acc[nt][reg];
    }
  }
  __syncthreads();
  for (int i = tid; i < OC * 64; i += 256) {
    int oc = i >> 6, p2 = i & 63;
    int g2 = blockIdx.x * 64 + p2;
    int n2 = g2 / HW, px2 = g2 % HW;
    dst[((size_t)n2 * OC + oc) * HW + px2] = ct[oc * 65 + p2] + bias[oc];
  }
}

// ---------------------------------------------------------------------------
// FUSED deformable conv (def3 + def5) as gather + implicit-GEMM bf16 MFMA.
// Block = 64 px (4 waves x 16 rows) x 64 oc. K-loop over 34 taps (9 from
// the 3x3 deform, 25 from the 5x5 deform), each tap a K=64 channel slab.
// Per tap: 256 threads bilinear-gather the 64px x 64c A-tile in f32
// (thread -> px = tid>>2, c-range = (tid&3)*16), convert to bf16, stage
// into LDS with XOR swizzle (byte ^= (px&7)<<4 — kills the 32-way bank
// conflict of a 128B-stride row-major tile), then 8 MFMA per wave.
// B frags prefetched to registers before the barrier (L1/L2-resident).
// Accumulates d3+d5 in f32; writes dsum directly (no c-split planes).
// ---------------------------------------------------------------------------
__global__ __launch_bounds__(256) void k_deform_mfma(
    const float* __restrict__ xT,
    const float* __restrict__ off3b, const float* __restrict__ off5b,
    const __hip_bfloat16* __restrict__ wBd,
    float* __restrict__ dsum)
{
  __shared__ __align__(16) short As[64 * 64];   // A tile [px][c] swizzled, 8 KB
  __shared__ float ct[64 * 65];                 // C transpose, 16.25 KB
  const int tid = threadIdx.x;
  const int w = tid >> 6, lane = tid & 63;
  const int quad = lane >> 4, mrow = lane & 15;
  // gather role
  const int pxl = tid >> 2, cq = tid & 3;
  const int gpx_g = blockIdx.x * 64 + pxl;
  const int n_g = gpx_g / HW, px_g = gpx_g % HW;
  const int y_g = px_g / WD, x_g = px_g % WD;
  const float* pt = xT + (size_t)n_g * HW * 64;
  const float* ob3 = off3b + (size_t)n_g * 18 * HW + px_g;
  const float* ob5 = off5b + (size_t)n_g * 50 * HW + px_g;
  // mfma role
  const int arow = w * 16 + mrow;
  const int sw2 = (arow & 7) << 4;

  f32x4 acc[4];
#pragma unroll
  for (int nt = 0; nt < 4; nt++) acc[nt] = (f32x4){0.f, 0.f, 0.f, 0.f};

  for (int tap = 0; tap < 34; tap++) {
    // prefetch this tap's B frags (uniform across waves -> L1 broadcast)
    const short* bw = (const short*)wBd + (size_t)tap * 4096;
    short8 bfrag[8];
#pragma unroll
    for (int q = 0; q < 8; q++)
      bfrag[q] = *(const short8*)(bw + q * 512 + lane * 8);

    // per-tap geometry + offsets (tap is wave-uniform)
    int kk, ty, tx, PADl; const float* obp;
    if (tap < 9) { kk = tap; ty = kk / 3; tx = kk % 3; PADl = 1; obp = ob3; }
    else         { kk = tap - 9; ty = kk / 5; tx = kk % 5; PADl = 2; obp = ob5; }
    float offy = obp[(2 * kk) * HW];
    float offx = obp[(2 * kk + 1) * HW];
    float py = (float)(y_g + ty - PADl) + offy;
    float pxx = (float)(x_g + tx - PADl) + offx;
    float fy = floorf(py), fx = floorf(pxx);
    int y0 = (int)fy, x0 = (int)fx;
    float ly = py - fy, lx = pxx - fx;
    int y1 = y0 + 1, x1 = x0 + 1;
    float vy0 = (y0 >= 0 && y0 < WD) ? 1.f : 0.f;
    float vy1 = (y1 >= 0 && y1 < WD) ? 1.f : 0.f;
    float vx0 = (x0 >= 0 && x0 < WD) ? 1.f : 0.f;
    float vx1 = (x1 >= 0 && x1 < WD) ? 1.f : 0.f;
    float w00 = (1.f - ly) * (1.f - lx) * vy0 * vx0;
    float w01 = (1.f - ly) * lx * vy0 * vx1;
    float w10 = ly * (1.f - lx) * vy1 * vx0;
    float w11 = ly * lx * vy1 * vx1;
    int cy0 = min(max(y0, 0), WD - 1), cy1 = min(max(y1, 0), WD - 1);
    int cx0 = min(max(x0, 0), WD - 1), cx1 = min(max(x1, 0), WD - 1);
    const float* p00 = pt + (cy0 * WD + cx0) * 64 + cq * 16;
    const float* p01 = pt + (cy0 * WD + cx1) * 64 + cq * 16;
    const float* p10 = pt + (cy1 * WD + cx0) * 64 + cq * 16;
    const float* p11 = pt + (cy1 * WD + cx1) * 64 + cq * 16;
    short8 h0, h1;
#pragma unroll
    for (int cb = 0; cb < 16; cb += 4) {
      float4 a = *(const float4*)(p00 + cb);
      float4 b = *(const float4*)(p01 + cb);
      float4 c4 = *(const float4*)(p10 + cb);
      float4 d = *(const float4*)(p11 + cb);
      float g0 = a.x * w00 + b.x * w01 + c4.x * w10 + d.x * w11;
      float g1 = a.y * w00 + b.y * w01 + c4.y * w10 + d.y * w11;
      float g2 = a.z * w00 + b.z * w01 + c4.z * w10 + d.z * w11;
      float g3 = a.w * w00 + b.w * w01 + c4.w * w10 + d.w * w11;
      __hip_bfloat16 q0 = __float2bfloat16(g0);
      __hip_bfloat16 q1 = __float2bfloat16(g1);
      __hip_bfloat16 q2 = __float2bfloat16(g2);
      __hip_bfloat16 q3 = __float2bfloat16(g3);
      if (cb < 8) {
        h0[cb + 0] = *(short*)&q0; h0[cb + 1] = *(short*)&q1;
        h0[cb + 2] = *(short*)&q2; h0[cb + 3] = *(short*)&q3;
      } else {
        h1[cb - 8] = *(short*)&q0; h1[cb - 7] = *(short*)&q1;
        h1[cb - 6] = *(short*)&q2; h1[cb - 5] = *(short*)&q3;
      }
    }
    __syncthreads();   // previous tap's MFMA reads of As complete
    {
      int b0 = pxl * 128 + cq * 32;
      int sw = (pxl & 7) << 4;
      *(short8*)((char*)As + (b0 ^ sw)) = h0;
      *(short8*)((char*)As + ((b0 + 16) ^ sw)) = h1;
    }
    __syncthreads();   // A tile visible
#pragma unroll
    for (int chunk = 0; chunk < 2; chunk++) {
      short8 a = *(const short8*)(
          (const char*)As + ((arow * 128 + chunk * 64 + quad * 16) ^ sw2));
#pragma unroll
      for (int nt = 0; nt < 4; nt++) {
        acc[nt] = __builtin_amdgcn_mfma_f32_16x16x32_bf16(
            a, bfrag[chunk * 4 + nt], acc[nt], 0, 0, 0);
      }
    }
  }
  // C/D frag: col(oc) = lane&15, row(px) = quad*4 + reg
#pragma unroll
  for (int nt = 0; nt < 4; nt++) {
    int oc_l = nt * 16 + mrow;
#pragma unroll
    for (int reg = 0; reg < 4; reg++) {
      int pxr = w * 16 + quad * 4 + reg;
      ct[oc_l * 65 + pxr] = acc[nt][reg];
    }
  }
  __syncthreads();
  for (int i = tid; i < 64 * 64; i += 256) {
    int oc = i >> 6, p2 = i & 63;
    int g2 = blockIdx.x * 64 + p2;
    int n2 = g2 / HW, px2 = g2 % HW;
    dsum[((size_t)n2 * 64 + oc) * HW + px2] = ct[oc * 65 + p2];
  }
}

// ---------------------------------------------------------------------------
// maxpool 3x3 + 1x1 conv (BN folded) + diff epilogue (dsum holds d3+d5).
// ---------------------------------------------------------------------------
__global__ __launch_bounds__(256) void k_davg_diff(
    const float* __restrict__ frames, const float* __restrict__ c1T,
    const float* __restrict__ B3, float* __restrict__ dsum)
{
  __shared__ float wl[64 * 32];
  const int tid = threadIdx.x;
  const int o0 = blockIdx.y * 32;
  for (int i = tid; i < 512; i += 256) {
    int c = i >> 3, q = i & 7;
    ((float4*)wl)[i] = *(const float4*)(c1T + c * 64 + o0 + q * 4);
  }
  __syncthreads();
  const int gpx = blockIdx.x * 256 + tid;
  const bool act = gpx < NPX;
  const int gpe = act ? gpx : 0;
  const int n = gpe / HW, px = gpe % HW;
  const int b = n / 7, t = n % 7;
  const int fpost = b * 8 + t + 1, fpre = b * 8 + t;
  const int y = px / WD, x = px % WD;
  int lin[9]; bool okm[9];
#pragma unroll
  for (int t2 = 0; t2 < 9; t2++) {
    int iy = y + t2 / 3 - 1, ix = x + t2 % 3 - 1;
    okm[t2] = iy >= 0 && iy < WD && ix >= 0 && ix < WD;
    lin[t2] = min(max(iy, 0), WD - 1) * WD + min(max(ix, 0), WD - 1);
  }
  float acc[32];
#pragma unroll
  for (int j = 0; j < 32; j++) acc[j] = 0.f;
  const float* sb = frames + (size_t)fpost * 64 * HW;
  for (int c = 0; c < 64; c++) {
    const float* p = sb + c * HW;
    float m = -1e30f;
#pragma unroll
    for (int t2 = 0; t2 < 9; t2++) {
      float v = okm[t2] ? p[lin[t2]] : -1e30f;
      m = fmaxf(m, v);
    }
    const float* wr = &wl[c * 32];
#pragma unroll
    for (int j = 0; j < 32; j++) acc[j] += m * wr[j];
  }
  if (act) {
    const float* xpre = frames + (size_t)fpre * 64 * HW + px;
    float* dp = dsum + (size_t)n * 64 * HW + px;
#pragma unroll
    for (int j = 0; j < 32; j++) {
      int o = o0 + j;
      float d = dp[o * HW] + (acc[j] + B3[o]) - 3.f * xpre[o * HW];
      dp[o * HW] = fabsf(d);
    }
  }
}

// ---------------------------------------------------------------------------
// Spatial mean of cat = [diff frames | t_out] per (nt, c).
// ---------------------------------------------------------------------------
__global__ void k_gmean(const float* __restrict__ dsum,
                        const float* __restrict__ t_out,
                        float* __restrict__ gmean)
{
  const int nt = blockIdx.x, c = blockIdx.y;
  const int b = nt >> 3, tt = nt & 7;
  const float* p = (tt < 7) ? (dsum + (size_t)((b * 7 + tt) * 64 + c) * HW)
                            : (t_out + (size_t)(b * 64 + c) * HW);
  const int tid = threadIdx.x;
  float s = 0.f;
  for (int i = tid; i < HW; i += 64) s += p[i];
#pragma unroll
  for (int o = 32; o > 0; o >>= 1) s += __shfl_down(s, o, 64);
  if (tid == 0) gmean[nt * 64 + c] = s * (1.f / HW);
}

// ---------------------------------------------------------------------------
// Gate: 1x1 conv 64->256 + sigmoid; store mult.
// ---------------------------------------------------------------------------
__global__ __launch_bounds__(256) void k_gate(
    const float* __restrict__ gmean, const float* __restrict__ gwT,
    const float* __restrict__ Bg, float* __restrict__ mult)
{
  __shared__ float gm[64];
  const int nt = blockIdx.x, co = threadIdx.x;
  if (co < 64) gm[co] = gmean[nt * 64 + co];
  __syncthreads();
  float a = 0.f;
#pragma unroll 8
  for (int c = 0; c < 64; c++) a += gm[c] * gwT[c * 256 + co];
  float pre = a + Bg[co];
  mult[nt * 256 + co] = 0.5f + 1.f / (1.f + expf(-pre));
}

// ---------------------------------------------------------------------------
// out = x * mult[nt,co]
// ---------------------------------------------------------------------------
__global__ void k_apply(const float* __restrict__ x,
                        const float* __restrict__ mult,
                        float* __restrict__ outp)
{
  const int i = blockIdx.x * 256 + threadIdx.x;
  const int plane = i / 196;
  const float m = mult[plane];
  float4 v = ((const float4*)x)[i];
  v.x *= m; v.y *= m; v.z *= m; v.w *= m;
  ((float4*)outp)[i] = v;
}

// ---------------------------------------------------------------------------
extern "C" void kernel_launch(void* const* d_in, const int* in_sizes, int n_in,
                              void* d_out, int out_size, void* d_ws, size_t ws_size,
                              hipStream_t stream)
{
  const float* x       = (const float*)d_in[0];
  const float* w_down  = (const float*)d_in[1];
  const float* b_down  = (const float*)d_in[2];
  const float* bn1_g   = (const float*)d_in[3];
  const float* bn1_b   = (const float*)d_in[4];
  const float* bn1_m   = (const float*)d_in[5];
  const float* bn1_v   = (const float*)d_in[6];
  const float* tconv_w = (const float*)d_in[7];
  const float* tconv_b = (const float*)d_in[8];
  const float* bnt_g   = (const float*)d_in[9];
  const float* bnt_b   = (const float*)d_in[10];
  const float* bnt_m   = (const float*)d_in[11];
  const float* bnt_v   = (const float*)d_in[12];
  const float* off3_w  = (const float*)d_in[13];
  const float* off3_b  = (const float*)d_in[14];
  const float* def3_w  = (const float*)d_in[15];
  const float* off5_w  = (const float*)d_in[16];
  const float* off5_b  = (const float*)d_in[17];
  const float* def5_w  = (const float*)d_in[18];
  const float* conv1_w = (const float*)d_in[19];
  const float* conv1_b = (const float*)d_in[20];
  const float* bn3_g   = (const float*)d_in[21];
  const float* bn3_b   = (const float*)d_in[22];
  const float* bn3_m   = (const float*)d_in[23];
  const float* bn3_v   = (const float*)d_in[24];
  const float* conv_w  = (const float*)d_in[25];
  const float* conv_b  = (const float*)d_in[26];
  const float* bn2_g   = (const float*)d_in[27];
  const float* bn2_b   = (const float*)d_in[28];
  const float* bn2_m   = (const float*)d_in[29];
  const float* bn2_v   = (const float*)d_in[30];

  float* ws = (float*)d_ws;
  float* out_b  = ws; ws += 64 * 64 * HW;
  float* U      = ws; ws += 8 * 192 * HW;
  float* t_out  = ws; ws += 8 * 64 * HW;
  float* off3b  = ws; ws += 56 * 18 * HW;
  float* off5b  = ws; ws += 56 * 50 * HW;
  float* dsum   = ws; ws += PLANE;
  float* gmean  = ws; ws += 64 * 64;
  float* multb  = ws; ws += 64 * 256;
  float* wdownT = ws; ws += 256 * 64;
  float* bias1  = ws; ws += 64;
  float* wtT    = ws; ws += 192 * 9 * 64;
  float* AtBt   = ws; ws += 128;
  float* c1T    = ws; ws += 64 * 64;
  float* B3     = ws; ws += 64;
  float* gwT    = ws; ws += 64 * 256;
  float* Bg     = ws; ws += 256;
  float* xT     = ws; ws += PLANE;                      // px-major f32
  __hip_bfloat16* wBs3 = (__hip_bfloat16*)ws; ws += 9216;    // 18432 bf16
  __hip_bfloat16* wBs5 = (__hip_bfloat16*)ws; ws += 51200;   // 102400 bf16
  __hip_bfloat16* wBd  = (__hip_bfloat16*)ws; ws += 69632;   // 139264 bf16
  __hip_bfloat16* xTbP = (__hip_bfloat16*)ws; ws += 56 * PADPX * 64 / 2;

  k_prep<<<256, 256, 0, stream>>>(
      w_down, b_down, bn1_g, bn1_b, bn1_m, bn1_v,
      tconv_w, tconv_b, bnt_g, bnt_b, bnt_m, bnt_v,
      off3_w, def3_w, off5_w, def5_w,
      conv1_w, conv1_b, bn3_g, bn3_b, bn3_m, bn3_v,
      conv_w, conv_b, bn2_g, bn2_b, bn2_m, bn2_v,
      wdownT, bias1, wtT, AtBt, wBs3, wBs5, wBd,
      c1T, B3, gwT, Bg);
  k_zerob<<<1792, 256, 0, stream>>>((float4*)xTbP);

  k_down<<<dim3(196, 2), 256, 0, stream>>>(x, wdownT, bias1, out_b);
  k_xpose<<<dim3(56, 13), 256, 0, stream>>>(out_b, xT, xTbP);
  k_makeU<<<1568, 256, 0, stream>>>(out_b, U);
  k_tconv<<<dim3(8, 4, 16), 256, 0, stream>>>(U, wtT, AtBt, t_out);
  // 686 blocks of 64 px each (43904 = 686*64 exact)
  k_offconv_mfma<3, 1, 18, 2, 9><<<686, 256, 0, stream>>>(xTbP, wBs3, off3_b, off3b);
  k_offconv_mfma<5, 2, 50, 4, 5><<<686, 256, 0, stream>>>(xTbP, wBs5, off5_b, off5b);
  k_deform_mfma<<<686, 256, 0, stream>>>(xT, off3b, off5b, wBd, dsum);
  k_davg_diff<<<dim3(PXBLK, 2), 256, 0, stream>>>(out_b, c1T, B3, dsum);
  k_gmean<<<dim3(64, 64), 64, 0, stream>>>(dsum, t_out, gmean);
  k_gate<<<64, 256, 0, stream>>>(gmean, gwT, Bg, multb);
  k_apply<<<12544, 256, 0, stream>>>(x, multb, (float*)d_out);
}

// Round 2
// 535.721 us; speedup vs baseline: 1.3277x; 1.0277x over previous
//
#include <hip/hip_runtime.h>
#include <hip/hip_bf16.h>

#define HW 784
#define WD 28
#define NPX (56 * HW)          // 43904 deform/offconv pixels
#define PXBLK 172              // ceil(43904/256)
#define PLANE (56 * 64 * HW)   // 2,809,856 floats: one full plane
#define PADPX 1024             // 32x32 padded spatial (halo 2)

using short8 = __attribute__((ext_vector_type(8))) short;
using f32x4  = __attribute__((ext_vector_type(4))) float;

// ---------------------------------------------------------------------------
// Prep: fold BN into transposed weight layouts + MFMA-fragment-order bf16
// weights for the offset convs and the fused deform GEMM.
// wBs[tap][chunk][ntile][lane][j] (bf16): B[k=chunk*32+(lane>>4)*8+j][oc=ntile*16+(lane&15)]
// wBd: same frag layout, 34 taps (9 from def3_w, 25 from def5_w), NT=4.
// ---------------------------------------------------------------------------
__global__ void k_prep(
    const float* __restrict__ w_down, const float* __restrict__ b_down,
    const float* __restrict__ bn1_g, const float* __restrict__ bn1_b,
    const float* __restrict__ bn1_m, const float* __restrict__ bn1_v,
    const float* __restrict__ tconv_w, const float* __restrict__ tconv_b,
    const float* __restrict__ bnt_g, const float* __restrict__ bnt_b,
    const float* __restrict__ bnt_m, const float* __restrict__ bnt_v,
    const float* __restrict__ off3_w, const float* __restrict__ def3_w,
    const float* __restrict__ off5_w, const float* __restrict__ def5_w,
    const float* __restrict__ conv1_w, const float* __restrict__ conv1_b,
    const float* __restrict__ bn3_g, const float* __restrict__ bn3_b,
    const float* __restrict__ bn3_m, const float* __restrict__ bn3_v,
    const float* __restrict__ conv_w, const float* __restrict__ conv_b,
    const float* __restrict__ bn2_g, const float* __restrict__ bn2_b,
    const float* __restrict__ bn2_m, const float* __restrict__ bn2_v,
    float* __restrict__ wdownT, float* __restrict__ bias1,
    float* __restrict__ wtT, float* __restrict__ AtBt,
    __hip_bfloat16* __restrict__ wBs3, __hip_bfloat16* __restrict__ wBs5,
    __hip_bfloat16* __restrict__ wBd,
    float* __restrict__ c1T, float* __restrict__ B3,
    float* __restrict__ gwT, float* __restrict__ Bg)
{
  const int tid = blockIdx.x * blockDim.x + threadIdx.x;
  const int nth = gridDim.x * blockDim.x;
  for (int i = tid; i < 256 * 64; i += nth) {
    int c = i >> 6, cr = i & 63;
    float s = bn1_g[cr] / sqrtf(bn1_v[cr] + 1e-5f);
    wdownT[i] = w_down[cr * 256 + c] * s;
  }
  for (int i = tid; i < 64; i += nth) {
    float s = bn1_g[i] / sqrtf(bn1_v[i] + 1e-5f);
    bias1[i] = (b_down[i] - bn1_m[i]) * s + bn1_b[i];
  }
  for (int i = tid; i < 192 * 9 * 64; i += nth) {
    int cc = i / (9 * 64); int tap = (i / 64) % 9; int o = i & 63;
    int dt = cc >> 6, c = cc & 63;
    wtT[i] = tconv_w[o * 1728 + c * 27 + dt * 9 + tap];
  }
  for (int i = tid; i < 64; i += nth) {
    float s = bnt_g[i] / sqrtf(bnt_v[i] + 1e-5f);
    AtBt[i] = s * 0.125f;
    AtBt[64 + i] = (tconv_b[i] - bnt_m[i]) * s + bnt_b[i];
  }
  // off3 MFMA B-frags: K2=9, NT=2 (ocpad 32). total 9*2*2*512 = 18432
  for (int i = tid; i < 9 * 2 * 2 * 512; i += nth) {
    int j = i & 7; int lane = (i >> 3) & 63;
    int rest = i >> 9; int nt = rest % 2; rest /= 2;
    int chunk = rest & 1; int tap = rest >> 1;
    int c = chunk * 32 + ((lane >> 4) << 3) + j;
    int oc = nt * 16 + (lane & 15);
    float v = (oc < 18) ? off3_w[oc * 576 + c * 9 + tap] : 0.f;
    wBs3[i] = __float2bfloat16(v);
  }
  // off5 MFMA B-frags: K2=25, NT=4 (ocpad 64). total 25*2*4*512 = 102400
  for (int i = tid; i < 25 * 2 * 4 * 512; i += nth) {
    int j = i & 7; int lane = (i >> 3) & 63;
    int rest = i >> 9; int nt = rest % 4; rest /= 4;
    int chunk = rest & 1; int tap = rest >> 1;
    int c = chunk * 32 + ((lane >> 4) << 3) + j;
    int oc = nt * 16 + (lane & 15);
    float v = (oc < 50) ? off5_w[oc * 1600 + c * 25 + tap] : 0.f;
    wBs5[i] = __float2bfloat16(v);
  }
  // fused deform B-frags: 34 taps (0..8 = def3, 9..33 = def5), NT=4 (oc=64)
  for (int i = tid; i < 34 * 2 * 4 * 512; i += nth) {
    int j = i & 7; int lane = (i >> 3) & 63;
    int rest = i >> 9; int nt = rest & 3; rest >>= 2;
    int chunk = rest & 1; int tap = rest >> 1;
    int c = chunk * 32 + ((lane >> 4) << 3) + j;
    int oc = nt * 16 + (lane & 15);
    float v = (tap < 9) ? def3_w[oc * 576 + c * 9 + tap]
                        : def5_w[oc * 1600 + c * 25 + (tap - 9)];
    wBd[i] = __float2bfloat16(v);
  }
  for (int i = tid; i < 64 * 64; i += nth) {
    int c = i >> 6, o = i & 63;
    float s = bn3_g[o] / sqrtf(bn3_v[o] + 1e-5f);
    c1T[i] = conv1_w[o * 64 + c] * s;
  }
  for (int i = tid; i < 64; i += nth) {
    float s = bn3_g[i] / sqrtf(bn3_v[i] + 1e-5f);
    B3[i] = (conv1_b[i] - bn3_m[i]) * s + bn3_b[i];
  }
  for (int i = tid; i < 64 * 256; i += nth) {
    int c = i >> 8, co = i & 255;
    float s = bn2_g[co] / sqrtf(bn2_v[co] + 1e-5f);
    gwT[i] = conv_w[co * 64 + c] * s;
  }
  for (int i = tid; i < 256; i += nth) {
    float s = bn2_g[i] / sqrtf(bn2_v[i] + 1e-5f);
    Bg[i] = (conv_b[i] - bn2_m[i]) * s + bn2_b[i];
  }
}

// ---------------------------------------------------------------------------
// Zero the padded bf16 image (halo must be 0 every call; ws is re-poisoned).
// 56*1024*64 bf16 = 458752 float4.
// ---------------------------------------------------------------------------
__global__ void k_zerob(float4* __restrict__ p)
{
  p[blockIdx.x * 256 + threadIdx.x] = make_float4(0.f, 0.f, 0.f, 0.f);
}

// ---------------------------------------------------------------------------
// 1x1 down conv (256->64) + BN fold. px-flat grid (196, o-split 2).
// ---------------------------------------------------------------------------
__global__ __launch_bounds__(256) void k_down(
    const float* __restrict__ x, const float* __restrict__ wdownT,
    const float* __restrict__ bias1, float* __restrict__ out)
{
  __shared__ float wl[256 * 32];            // 32 KB
  const int tid = threadIdx.x;
  const int o0 = blockIdx.y * 32;
  for (int i = tid; i < 2048; i += 256) {
    int c = i >> 3, q = i & 7;
    ((float4*)wl)[i] = *(const float4*)(wdownT + c * 64 + o0 + q * 4);
  }
  __syncthreads();
  const int gpx = blockIdx.x * 256 + tid;   // < 50176 exact
  const int f = gpx / HW, px = gpx % HW;
  const float* xp = x + (size_t)f * 256 * HW + px;
  float acc[32];
#pragma unroll
  for (int j = 0; j < 32; j++) acc[j] = 0.f;
#pragma unroll 4
  for (int c = 0; c < 256; c++) {
    float xv = xp[c * HW];
    const float* wr = &wl[c * 32];
#pragma unroll
    for (int j = 0; j < 32; j++) acc[j] += xv * wr[j];
  }
  float* op = out + (size_t)f * 64 * HW + px;
#pragma unroll
  for (int j = 0; j < 32; j++) op[(o0 + j) * HW] = acc[j] + bias1[o0 + j];
}

// ---------------------------------------------------------------------------
// Transpose post frames to px-major: xT[n][px][c] (f32, for deform) and
// padded bf16 xTbP[n][(py+2)*32+(px+2)][c] (for MFMA offconvs).
// ---------------------------------------------------------------------------
__global__ __launch_bounds__(256) void k_xpose(
    const float* __restrict__ out_b, float* __restrict__ xT,
    __hip_bfloat16* __restrict__ xTbP)
{
  __shared__ float t[64 * 65];
  const int tid = threadIdx.x;
  const int lane = tid & 63, grp = tid >> 6;
  const int n = blockIdx.x;
  const int f = (n / 7) * 8 + (n % 7) + 1;
  const int px0 = blockIdx.y * 64;
  const float* sb = out_b + (size_t)f * 64 * HW;
#pragma unroll
  for (int c = grp; c < 64; c += 4) {
    int px = px0 + lane;
    t[c * 65 + lane] = (px < HW) ? sb[c * HW + px] : 0.f;
  }
  __syncthreads();
#pragma unroll
  for (int r = grp; r < 64; r += 4) {
    int px = px0 + r;
    if (px < HW) {
      float v = t[lane * 65 + r];
      xT[((size_t)n * HW + px) * 64 + lane] = v;
      int py = px / WD, pxc = px % WD;
      xTbP[((size_t)n * PADPX + (py + 2) * 32 + (pxc + 2)) * 64 + lane] =
          __float2bfloat16(v);
    }
  }
}

// ---------------------------------------------------------------------------
// U planes for collapsed temporal conv.
// ---------------------------------------------------------------------------
__global__ void k_makeU(const float* __restrict__ out, float* __restrict__ U)
{
  const int idx = blockIdx.x * 256 + threadIdx.x;
  const int b = idx / (64 * HW);
  const int r = idx % (64 * HW);
  const float* p = out + (size_t)b * 8 * 64 * HW + r;
  float v0 = p[0];
  float s = v0, v = v0;
#pragma unroll
  for (int t = 1; t < 8; t++) { v = p[t * 64 * HW]; s += v; }
  float* u = U + (size_t)b * 192 * HW + r;
  u[0] = s - v;
  u[64 * HW] = s;
  u[128 * HW] = s - v0;
}

// ---------------------------------------------------------------------------
// Collapsed temporal conv: 3x3, 192->64. o-groups of 4 (16 z-blocks).
// ---------------------------------------------------------------------------
__global__ __launch_bounds__(256) void k_tconv(
    const float* __restrict__ U, const float* __restrict__ wtT,
    const float* __restrict__ AtBt, float* __restrict__ t_out)
{
  __shared__ float wl[16 * 9 * 4];
  const int tid = threadIdx.x;
  const int b = blockIdx.x;
  const int px = blockIdx.y * 256 + tid;
  const int o0 = blockIdx.z * 4;
  const bool act = px < HW;
  const int pxe = act ? px : 0;
  const int y = pxe / WD, x = pxe % WD;
  int lin[9]; float msk[9];
#pragma unroll
  for (int t = 0; t < 9; t++) {
    int iy = y + t / 3 - 1, ix = x + t % 3 - 1;
    bool ok = iy >= 0 && iy < WD && ix >= 0 && ix < WD;
    lin[t] = min(max(iy, 0), WD - 1) * WD + min(max(ix, 0), WD - 1);
    msk[t] = ok ? 1.f : 0.f;
  }
  float acc[4];
#pragma unroll
  for (int j = 0; j < 4; j++) acc[j] = 0.f;
  const float* ub = U + (size_t)b * 192 * HW;
  for (int ccb = 0; ccb < 12; ccb++) {
    __syncthreads();
    for (int i = tid; i < 576; i += 256) {
      int ccL = i / 36; int rr = i % 36; int tap = rr >> 2; int j = rr & 3;
      wl[i] = wtT[((ccb * 16 + ccL) * 9 + tap) * 64 + o0 + j];
    }
    __syncthreads();
    for (int ccL = 0; ccL < 16; ccL++) {
      const float* p = ub + (ccb * 16 + ccL) * HW;
      float v[9];
#pragma unroll
      for (int t = 0; t < 9; t++) v[t] = p[lin[t]] * msk[t];
      const float* wr = &wl[ccL * 36];
#pragma unroll
      for (int t = 0; t < 9; t++)
#pragma unroll
        for (int j = 0; j < 4; j++) acc[j] += v[t] * wr[t * 4 + j];
    }
  }
  if (act) {
#pragma unroll
    for (int j = 0; j < 4; j++) {
      int o = o0 + j;
      t_out[(size_t)(b * 64 + o) * HW + px] = acc[j] * AtBt[o] + AtBt[64 + o];
    }
  }
}

// ---------------------------------------------------------------------------
// Offset convs as implicit-GEMM bf16 MFMA (16x16x32).
// ---------------------------------------------------------------------------
template <int KS, int PAD, int OC, int NT, int TAPBLK>
__global__ __launch_bounds__(256) void k_offconv_mfma(
    const __hip_bfloat16* __restrict__ xTbP,
    const __hip_bfloat16* __restrict__ wBs,
    const float* __restrict__ bias, float* __restrict__ dst)
{
  constexpr int K2 = KS * KS;
  __shared__ short bs[TAPBLK * NT * 1024];   // B frags, 2*NT KB per tap
  __shared__ float ct[NT * 16 * 65];         // C tile [ocpad][px(64)+pad]
  const int tid = threadIdx.x;
  const int w = tid >> 6, lane = tid & 63;
  const int quad = lane >> 4, mrow = lane & 15;
  const int gpx = blockIdx.x * 64 + w * 16 + mrow;   // A-row pixel
  const int n = gpx / HW, px = gpx % HW;
  const int y = px / WD, x = px % WD;
  const short* xb = (const short*)xTbP + ((size_t)n * PADPX) * 64;
  f32x4 acc[NT];
#pragma unroll
  for (int nt = 0; nt < NT; nt++) acc[nt] = (f32x4){0.f, 0.f, 0.f, 0.f};

  for (int tb = 0; tb < K2; tb += TAPBLK) {
    __syncthreads();
    for (int i = tid; i < TAPBLK * NT * 128; i += 256)
      ((float4*)bs)[i] = ((const float4*)(wBs + (size_t)tb * NT * 1024))[i];
    __syncthreads();
#pragma unroll
    for (int t2 = 0; t2 < TAPBLK; t2++) {
      int tap = tb + t2;
      if (K2 % TAPBLK != 0 && tap >= K2) break;
      int ty = tap / KS, tx = tap % KS;
      int sp = (y + ty + (2 - PAD)) * 32 + (x + tx + (2 - PAD));
      const short* ap = xb + sp * 64 + quad * 8;
      short8 a0 = *(const short8*)(ap);
      short8 a1 = *(const short8*)(ap + 32);
      const short* bp = bs + t2 * NT * 1024;
#pragma unroll
      for (int nt = 0; nt < NT; nt++) {
        short8 b0 = *(const short8*)(bp + nt * 512 + lane * 8);
        acc[nt] = __builtin_amdgcn_mfma_f32_16x16x32_bf16(a0, b0, acc[nt], 0, 0, 0);
      }
#pragma unroll
      for (int nt = 0; nt < NT; nt++) {
        short8 b1 = *(const short8*)(bp + (NT + nt) * 512 + lane * 8);
        acc[nt] = __builtin_amdgcn_mfma_f32_16x16x32_bf16(a1, b1, acc[nt], 0, 0, 0);
      }
    }
  }
  // C/D frag: col(oc) = lane&15, row(px) = quad*4 + reg
  __syncthreads();
#pragma unroll
  for (int nt = 0; nt < NT; nt++) {
    int oc_l = nt * 16 + mrow;
#pragma unroll
    for (int reg = 0; reg < 4; reg++) {
      int pxr = w * 16 + quad * 4 + reg;
      ct[oc_l * 65 + pxr] = acc[nt][reg];
    }
  }
  __syncthreads();
  for (int i = tid; i < OC * 64; i += 256) {
    int oc = i >> 6, p2 = i & 63;
    int g2 = blockIdx.x * 64 + p2;
    int n2 = g2 / HW, px2 = g2 % HW;
    dst[((size_t)n2 * OC + oc) * HW + px2] = ct[oc * 65 + p2] + bias[oc];
  }
}

// ---------------------------------------------------------------------------
// FUSED deformable conv (def3 + def5): gather + implicit-GEMM bf16 MFMA,
// WAVE-PRIVATE tiles, ZERO barriers.
// Grid = 2744 one-wave blocks; each wave owns 16 px x 64 oc (784 = 49*16,
// so a tile never crosses a frame). K-loop over 34 taps (9 def3 + 25 def5),
// each tap a K=64 channel slab:
//   - all 68 offset planes for the tile staged to LDS once (coalesced);
//   - per tap: lane gathers 16 channels (px = lane>>2, c0 = (lane&3)*16)
//     bilinearly in f32, converts to bf16, writes its wave-private
//     double-buffered XOR-swizzled LDS A-tile, then 8 MFMAs.
// In-wave LDS ordering (lockstep wave64 + lgkmcnt) replaces __syncthreads;
// #pragma unroll 2 makes the double-buffer index literal so the compiler
// can hoist tap t+1's global gathers above tap t's MFMAs.
// Epilogue: wave-private LDS transpose (reusing offset buffer) ->
// 16-float-contiguous coalesced stores. dsum = d3+d5 (f32), no c-split.
// ---------------------------------------------------------------------------
__global__ __launch_bounds__(64) void k_deform_mfma(
    const float* __restrict__ xT,
    const float* __restrict__ off3b, const float* __restrict__ off5b,
    const __hip_bfloat16* __restrict__ wBd,
    float* __restrict__ dsum)
{
  __shared__ __align__(16) short As[2 * 16 * 64];   // double-buffered A, 4 KB
  __shared__ __align__(16) float fsm[68 * 16];      // offsets, then C-xpose
  const int lane = threadIdx.x;
  const int tile = blockIdx.x;
  const int n = tile / 49, px0 = (tile % 49) * 16;
  const int quad = lane >> 4, mrow = lane & 15;
  const int pxl = lane >> 2, cq = lane & 3;
  const int swr = (mrow & 7) << 4;
  const int y_g = (px0 + pxl) / WD, x_g = (px0 + pxl) % WD;
  const float* pt = xT + (size_t)n * HW * 64;

  // stage all 68 offset planes for these 16 px (coalesced 64B runs)
  {
    const float* o3 = off3b + (size_t)n * 18 * HW + px0;
    const float* o5 = off5b + (size_t)n * 50 * HW + px0 - (size_t)18 * HW;
    for (int idx = lane; idx < 68 * 16; idx += 64) {
      int j = idx >> 4, p = idx & 15;
      const float* src = (j < 18) ? (o3 + j * HW + p) : (o5 + j * HW + p);
      fsm[idx] = *src;
    }
  }

  f32x4 acc[4];
#pragma unroll
  for (int nt = 0; nt < 4; nt++) acc[nt] = (f32x4){0.f, 0.f, 0.f, 0.f};

#pragma unroll 2
  for (int tap = 0; tap < 34; tap++) {
    // B frags for this tap (uniform per wave -> L1 broadcast)
    const short* bw = (const short*)wBd + (size_t)tap * 4096 + lane * 8;
    short8 bfrag[8];
#pragma unroll
    for (int q = 0; q < 8; q++)
      bfrag[q] = *(const short8*)(bw + q * 512);

    int kk, ty, tx, PADl, jb;
    if (tap < 9) { kk = tap; ty = kk / 3; tx = kk % 3; PADl = 1; jb = 0; }
    else { kk = tap - 9; ty = kk / 5; tx = kk % 5; PADl = 2; jb = 18; }
    float offy = fsm[(jb + 2 * kk) * 16 + pxl];
    float offx = fsm[(jb + 2 * kk + 1) * 16 + pxl];
    float py = (float)(y_g + ty - PADl) + offy;
    float pxx = (float)(x_g + tx - PADl) + offx;
    float fy = floorf(py), fx = floorf(pxx);
    int y0 = (int)fy, x0 = (int)fx;
    float ly = py - fy, lx = pxx - fx;
    int y1 = y0 + 1, x1 = x0 + 1;
    float vy0 = (y0 >= 0 && y0 < WD) ? 1.f : 0.f;
    float vy1 = (y1 >= 0 && y1 < WD) ? 1.f : 0.f;
    float vx0 = (x0 >= 0 && x0 < WD) ? 1.f : 0.f;
    float vx1 = (x1 >= 0 && x1 < WD) ? 1.f : 0.f;
    float w00 = (1.f - ly) * (1.f - lx) * vy0 * vx0;
    float w01 = (1.f - ly) * lx * vy0 * vx1;
    float w10 = ly * (1.f - lx) * vy1 * vx0;
    float w11 = ly * lx * vy1 * vx1;
    int cy0 = min(max(y0, 0), WD - 1), cy1 = min(max(y1, 0), WD - 1);
    int cx0 = min(max(x0, 0), WD - 1), cx1 = min(max(x1, 0), WD - 1);
    const float* p00 = pt + (cy0 * WD + cx0) * 64 + cq * 16;
    const float* p01 = pt + (cy0 * WD + cx1) * 64 + cq * 16;
    const float* p10 = pt + (cy1 * WD + cx0) * 64 + cq * 16;
    const float* p11 = pt + (cy1 * WD + cx1) * 64 + cq * 16;
    short8 h0, h1;
#pragma unroll
    for (int cb = 0; cb < 16; cb += 4) {
      float4 a = *(const float4*)(p00 + cb);
      float4 b = *(const float4*)(p01 + cb);
      float4 c4 = *(const float4*)(p10 + cb);
      float4 d = *(const float4*)(p11 + cb);
      float g0 = a.x * w00 + b.x * w01 + c4.x * w10 + d.x * w11;
      float g1 = a.y * w00 + b.y * w01 + c4.y * w10 + d.y * w11;
      float g2 = a.z * w00 + b.z * w01 + c4.z * w10 + d.z * w11;
      float g3 = a.w * w00 + b.w * w01 + c4.w * w10 + d.w * w11;
      __hip_bfloat16 q0 = __float2bfloat16(g0);
      __hip_bfloat16 q1 = __float2bfloat16(g1);
      __hip_bfloat16 q2 = __float2bfloat16(g2);
      __hip_bfloat16 q3 = __float2bfloat16(g3);
      if (cb < 8) {
        h0[cb + 0] = *(short*)&q0; h0[cb + 1] = *(short*)&q1;
        h0[cb + 2] = *(short*)&q2; h0[cb + 3] = *(short*)&q3;
      } else {
        h1[cb - 8] = *(short*)&q0; h1[cb - 7] = *(short*)&q1;
        h1[cb - 6] = *(short*)&q2; h1[cb - 5] = *(short*)&q3;
      }
    }
    // wave-private A tile: write swizzled (in-wave lgkmcnt ordering only)
    {
      char* dstb = (char*)(As + (tap & 1) * 1024);
      int b0 = pxl * 128 + cq * 32;
      int sw = (pxl & 7) << 4;
      *(short8*)(dstb + (b0 ^ sw)) = h0;
      *(short8*)(dstb + ((b0 + 16) ^ sw)) = h1;
    }
    const char* srcb = (const char*)(As + (tap & 1) * 1024);
    short8 a0 = *(const short8*)(srcb + ((mrow * 128 + quad * 16) ^ swr));
    short8 a1 = *(const short8*)(srcb + ((mrow * 128 + 64 + quad * 16) ^ swr));
#pragma unroll
    for (int nt = 0; nt < 4; nt++)
      acc[nt] = __builtin_amdgcn_mfma_f32_16x16x32_bf16(a0, bfrag[nt], acc[nt], 0, 0, 0);
#pragma unroll
    for (int nt = 0; nt < 4; nt++)
      acc[nt] = __builtin_amdgcn_mfma_f32_16x16x32_bf16(a1, bfrag[4 + nt], acc[nt], 0, 0, 0);
  }

  // epilogue: reuse fsm as ct[64 oc][17]; wave-internal ordering suffices
  // C/D frag: col(oc) = lane&15 (+nt*16), row(px) = quad*4 + reg
#pragma unroll
  for (int nt = 0; nt < 4; nt++) {
    int oc_l = nt * 16 + mrow;
#pragma unroll
    for (int reg = 0; reg < 4; reg++)
      fsm[oc_l * 17 + quad * 4 + reg] = acc[nt][reg];
  }
  {
    const int oc = lane;
    float* dp = dsum + ((size_t)n * 64 + oc) * HW + px0;
    float v[16];
#pragma unroll
    for (int i = 0; i < 16; i++) v[i] = fsm[oc * 17 + i];
#pragma unroll
    for (int q = 0; q < 4; q++) {
      float4 o4 = make_float4(v[q * 4], v[q * 4 + 1], v[q * 4 + 2], v[q * 4 + 3]);
      *(float4*)(dp + q * 4) = o4;
    }
  }
}

// ---------------------------------------------------------------------------
// maxpool 3x3 + 1x1 conv (BN folded) + diff epilogue (dsum holds d3+d5).
// ---------------------------------------------------------------------------
__global__ __launch_bounds__(256) void k_davg_diff(
    const float* __restrict__ frames, const float* __restrict__ c1T,
    const float* __restrict__ B3, float* __restrict__ dsum)
{
  __shared__ float wl[64 * 32];
  const int tid = threadIdx.x;
  const int o0 = blockIdx.y * 32;
  for (int i = tid; i < 512; i += 256) {
    int c = i >> 3, q = i & 7;
    ((float4*)wl)[i] = *(const float4*)(c1T + c * 64 + o0 + q * 4);
  }
  __syncthreads();
  const int gpx = blockIdx.x * 256 + tid;
  const bool act = gpx < NPX;
  const int gpe = act ? gpx : 0;
  const int n = gpe / HW, px = gpe % HW;
  const int b = n / 7, t = n % 7;
  const int fpost = b * 8 + t + 1, fpre = b * 8 + t;
  const int y = px / WD, x = px % WD;
  int lin[9]; bool okm[9];
#pragma unroll
  for (int t2 = 0; t2 < 9; t2++) {
    int iy = y + t2 / 3 - 1, ix = x + t2 % 3 - 1;
    okm[t2] = iy >= 0 && iy < WD && ix >= 0 && ix < WD;
    lin[t2] = min(max(iy, 0), WD - 1) * WD + min(max(ix, 0), WD - 1);
  }
  float acc[32];
#pragma unroll
  for (int j = 0; j < 32; j++) acc[j] = 0.f;
  const float* sb = frames + (size_t)fpost * 64 * HW;
  for (int c = 0; c < 64; c++) {
    const float* p = sb + c * HW;
    float m = -1e30f;
#pragma unroll
    for (int t2 = 0; t2 < 9; t2++) {
      float v = okm[t2] ? p[lin[t2]] : -1e30f;
      m = fmaxf(m, v);
    }
    const float* wr = &wl[c * 32];
#pragma unroll
    for (int j = 0; j < 32; j++) acc[j] += m * wr[j];
  }
  if (act) {
    const float* xpre = frames + (size_t)fpre * 64 * HW + px;
    float* dp = dsum + (size_t)n * 64 * HW + px;
#pragma unroll
    for (int j = 0; j < 32; j++) {
      int o = o0 + j;
      float d = dp[o * HW] + (acc[j] + B3[o]) - 3.f * xpre[o * HW];
      dp[o * HW] = fabsf(d);
    }
  }
}

// ---------------------------------------------------------------------------
// Spatial mean of cat = [diff frames | t_out] per (nt, c).
// ---------------------------------------------------------------------------
__global__ void k_gmean(const float* __restrict__ dsum,
                        const float* __restrict__ t_out,
                        float* __restrict__ gmean)
{
  const int nt = blockIdx.x, c = blockIdx.y;
  const int b = nt >> 3, tt = nt & 7;
  const float* p = (tt < 7) ? (dsum + (size_t)((b * 7 + tt) * 64 + c) * HW)
                            : (t_out + (size_t)(b * 64 + c) * HW);
  const int tid = threadIdx.x;
  float s = 0.f;
  for (int i = tid; i < HW; i += 64) s += p[i];
#pragma unroll
  for (int o = 32; o > 0; o >>= 1) s += __shfl_down(s, o, 64);
  if (tid == 0) gmean[nt * 64 + c] = s * (1.f / HW);
}

// ---------------------------------------------------------------------------
// Gate: 1x1 conv 64->256 + sigmoid; store mult.
// ---------------------------------------------------------------------------
__global__ __launch_bounds__(256) void k_gate(
    const float* __restrict__ gmean, const float* __restrict__ gwT,
    const float* __restrict__ Bg, float* __restrict__ mult)
{
  __shared__ float gm[64];
  const int nt = blockIdx.x, co = threadIdx.x;
  if (co < 64) gm[co] = gmean[nt * 64 + co];
  __syncthreads();
  float a = 0.f;
#pragma unroll 8
  for (int c = 0; c < 64; c++) a += gm[c] * gwT[c * 256 + co];
  float pre = a + Bg[co];
  mult[nt * 256 + co] = 0.5f + 1.f / (1.f + expf(-pre));
}

// ---------------------------------------------------------------------------
// out = x * mult[nt,co]
// ---------------------------------------------------------------------------
__global__ void k_apply(const float* __restrict__ x,
                        const float* __restrict__ mult,
                        float* __restrict__ outp)
{
  const int i = blockIdx.x * 256 + threadIdx.x;
  const int plane = i / 196;
  const float m = mult[plane];
  float4 v = ((const float4*)x)[i];
  v.x *= m; v.y *= m; v.z *= m; v.w *= m;
  ((float4*)outp)[i] = v;
}

// ---------------------------------------------------------------------------
extern "C" void kernel_launch(void* const* d_in, const int* in_sizes, int n_in,
                              void* d_out, int out_size, void* d_ws, size_t ws_size,
                              hipStream_t stream)
{
  const float* x       = (const float*)d_in[0];
  const float* w_down  = (const float*)d_in[1];
  const float* b_down  = (const float*)d_in[2];
  const float* bn1_g   = (const float*)d_in[3];
  const float* bn1_b   = (const float*)d_in[4];
  const float* bn1_m   = (const float*)d_in[5];
  const float* bn1_v   = (const float*)d_in[6];
  const float* tconv_w = (const float*)d_in[7];
  const float* tconv_b = (const float*)d_in[8];
  const float* bnt_g   = (const float*)d_in[9];
  const float* bnt_b   = (const float*)d_in[10];
  const float* bnt_m   = (const float*)d_in[11];
  const float* bnt_v   = (const float*)d_in[12];
  const float* off3_w  = (const float*)d_in[13];
  const float* off3_b  = (const float*)d_in[14];
  const float* def3_w  = (const float*)d_in[15];
  const float* off5_w  = (const float*)d_in[16];
  const float* off5_b  = (const float*)d_in[17];
  const float* def5_w  = (const float*)d_in[18];
  const float* conv1_w = (const float*)d_in[19];
  const float* conv1_b = (const float*)d_in[20];
  const float* bn3_g   = (const float*)d_in[21];
  const float* bn3_b   = (const float*)d_in[22];
  const float* bn3_m   = (const float*)d_in[23];
  const float* bn3_v   = (const float*)d_in[24];
  const float* conv_w  = (const float*)d_in[25];
  const float* conv_b  = (const float*)d_in[26];
  const float* bn2_g   = (const float*)d_in[27];
  const float* bn2_b   = (const float*)d_in[28];
  const float* bn2_m   = (const float*)d_in[29];
  const float* bn2_v   = (const float*)d_in[30];

  float* ws = (float*)d_ws;
  float* out_b  = ws; ws += 64 * 64 * HW;
  float* U      = ws; ws += 8 * 192 * HW;
  float* t_out  = ws; ws += 8 * 64 * HW;
  float* off3b  = ws; ws += 56 * 18 * HW;
  float* off5b  = ws; ws += 56 * 50 * HW;
  float* dsum   = ws; ws += PLANE;
  float* gmean  = ws; ws += 64 * 64;
  float* multb  = ws; ws += 64 * 256;
  float* wdownT = ws; ws += 256 * 64;
  float* bias1  = ws; ws += 64;
  float* wtT    = ws; ws += 192 * 9 * 64;
  float* AtBt   = ws; ws += 128;
  float* c1T    = ws; ws += 64 * 64;
  float* B3     = ws; ws += 64;
  float* gwT    = ws; ws += 64 * 256;
  float* Bg     = ws; ws += 256;
  float* xT     = ws; ws += PLANE;                      // px-major f32
  __hip_bfloat16* wBs3 = (__hip_bfloat16*)ws; ws += 9216;    // 18432 bf16
  __hip_bfloat16* wBs5 = (__hip_bfloat16*)ws; ws += 51200;   // 102400 bf16
  __hip_bfloat16* wBd  = (__hip_bfloat16*)ws; ws += 69632;   // 139264 bf16
  __hip_bfloat16* xTbP = (__hip_bfloat16*)ws; ws += 56 * PADPX * 64 / 2;

  k_prep<<<256, 256, 0, stream>>>(
      w_down, b_down, bn1_g, bn1_b, bn1_m, bn1_v,
      tconv_w, tconv_b, bnt_g, bnt_b, bnt_m, bnt_v,
      off3_w, def3_w, off5_w, def5_w,
      conv1_w, conv1_b, bn3_g, bn3_b, bn3_m, bn3_v,
      conv_w, conv_b, bn2_g, bn2_b, bn2_m, bn2_v,
      wdownT, bias1, wtT, AtBt, wBs3, wBs5, wBd,
      c1T, B3, gwT, Bg);
  k_zerob<<<1792, 256, 0, stream>>>((float4*)xTbP);

  k_down<<<dim3(196, 2), 256, 0, stream>>>(x, wdownT, bias1, out_b);
  k_xpose<<<dim3(56, 13), 256, 0, stream>>>(out_b, xT, xTbP);
  k_makeU<<<1568, 256, 0, stream>>>(out_b, U);
  k_tconv<<<dim3(8, 4, 16), 256, 0, stream>>>(U, wtT, AtBt, t_out);
  // 686 blocks of 64 px each (43904 = 686*64 exact)
  k_offconv_mfma<3, 1, 18, 2, 9><<<686, 256, 0, stream>>>(xTbP, wBs3, off3_b, off3b);
  k_offconv_mfma<5, 2, 50, 4, 5><<<686, 256, 0, stream>>>(xTbP, wBs5, off5_b, off5b);
  // 2744 wave-tiles of 16 px (43904 = 2744*16 exact; 784 = 49*16)
  k_deform_mfma<<<2744, 64, 0, stream>>>(xT, off3b, off5b, wBd, dsum);
  k_davg_diff<<<dim3(PXBLK, 2), 256, 0, stream>>>(out_b, c1T, B3, dsum);
  k_gmean<<<dim3(64, 64), 64, 0, stream>>>(dsum, t_out, gmean);
  k_gate<<<64, 256, 0, stream>>>(gmean, gwT, Bg, multb);
  k_apply<<<12544, 256, 0, stream>>>(x, multb, (float*)d_out);
}